// Round 5
// baseline (252.475 us; speedup 1.0000x reference)
//
#include <hip/hip_runtime.h>
#include <math.h>

#define SEQ    2048
#define BATCH  2
#define DMODEL 1024
#define NHEADS 16
#define DK     64

typedef __attribute__((ext_vector_type(8))) short  bf16x8;
typedef __attribute__((ext_vector_type(4))) float  f32x4;
typedef __attribute__((ext_vector_type(8))) unsigned short u16x8;

// async global->LDS, 16B per lane. LDS dest must be uniform_base + lane*16.
#define GLD16(gp, lp) __builtin_amdgcn_global_load_lds(                      \
    (__attribute__((address_space(1))) void*)(gp),                            \
    (__attribute__((address_space(3))) void*)(lp), 16, 0, 0)

__device__ inline unsigned short f2bf(float f) {
    unsigned int u = __float_as_uint(f);
    u += 0x7fffu + ((u >> 16) & 1u);   // round-to-nearest-even
    return (unsigned short)(u >> 16);
}

// pack two f32 -> two bf16 in one u32 (v_cvt_pk_bf16_f32 on gfx950)
__device__ inline unsigned int pk2bf(float a, float b) {
#if __has_builtin(__builtin_amdgcn_cvt_pk_bf16_f32)
    typedef __attribute__((ext_vector_type(2))) __bf16 v2bf;
    v2bf r = __builtin_amdgcn_cvt_pk_bf16_f32(a, b);
    unsigned int u; __builtin_memcpy(&u, &r, 4); return u;
#else
    return (unsigned int)f2bf(a) | ((unsigned int)f2bf(b) << 16);
#endif
}

__device__ inline float fast_exp2(float x) {
#if __has_builtin(__builtin_amdgcn_exp2f)
    return __builtin_amdgcn_exp2f(x);
#else
    return __expf(x * 0.69314718055994531f);
#endif
}

// workspace layout (ushort units)
#define WS_QB   0u
#define WS_KB   4194304u
#define WS_VB   8388608u
#define WS_WIB  12582912u
#define WS_WOB  15728640u
#define WS_QH   16777216u
#define WS_KH   20971520u
#define WS_VT   25165824u
#define WS_ATT  29360128u

// ---------------------------------------------------------------------------
// Cast all f32 inputs to bf16 in workspace. 8 floats / thread.
// ---------------------------------------------------------------------------
__global__ __launch_bounds__(256) void cast_all_kernel(
    const float* __restrict__ q, const float* __restrict__ k,
    const float* __restrict__ v, const float* __restrict__ w_in,
    const float* __restrict__ w_out, unsigned short* __restrict__ ws)
{
    const int gid = blockIdx.x * 256 + threadIdx.x;   // 0..2097151
    const float* src; unsigned short* dst;
    if (gid < 524288)       { int g = gid;           src = q     + (size_t)g*8; dst = ws + WS_QB  + (size_t)g*8; }
    else if (gid < 1048576) { int g = gid - 524288;  src = k     + (size_t)g*8; dst = ws + WS_KB  + (size_t)g*8; }
    else if (gid < 1572864) { int g = gid - 1048576; src = v     + (size_t)g*8; dst = ws + WS_VB  + (size_t)g*8; }
    else if (gid < 1966080) { int g = gid - 1572864; src = w_in  + (size_t)g*8; dst = ws + WS_WIB + (size_t)g*8; }
    else                    { int g = gid - 1966080; src = w_out + (size_t)g*8; dst = ws + WS_WOB + (size_t)g*8; }
    float4 a = *(const float4*)src;
    float4 b = *(const float4*)(src + 4);
    u16x8 o;
    o[0]=f2bf(a.x); o[1]=f2bf(a.y); o[2]=f2bf(a.z); o[3]=f2bf(a.w);
    o[4]=f2bf(b.x); o[5]=f2bf(b.y); o[6]=f2bf(b.z); o[7]=f2bf(b.w);
    *(u16x8*)dst = o;
}

// ---------------------------------------------------------------------------
// QKV projection GEMM-BT (MFMA): C[m][n] = sum_k A[m][k]*W[n][k] + bias[n]
// 128x128 tile, BK=32, XOR-swizzled LDS.
// Q output pre-scaled by 0.125*log2(e) (softmax base-2 domain).
// V output stored transposed (bh, d, s), pair-packed 4B stores.
// ---------------------------------------------------------------------------
__global__ __launch_bounds__(256) void qkv_gemm_kernel(
    const unsigned short* __restrict__ ws_in, const float* __restrict__ bias,
    unsigned short* __restrict__ ws_out)
{
    __shared__ unsigned short As[128*32];
    __shared__ unsigned short Bs[128*32];

    const int t    = threadIdx.x;
    const int lane = t & 63;
    const int w    = t >> 6;
    const int lrow = lane & 15;
    const int quad = lane >> 4;
    const int wm   = (w >> 1) * 64;
    const int wn   = (w & 1) * 64;

    const int n0    = blockIdx.x * 128;
    const int m0    = blockIdx.y * 128;
    const int which = n0 >> 10;            // 0=q,1=k,2=v

    const unsigned short* A = ws_in + WS_QB + (size_t)which * 4194304u;
    const unsigned short* B = ws_in + WS_WIB;

    const int srow = t >> 2;
    const int scc  = (t & 3) ^ ((t >> 3) & 3);
    const unsigned short* gA0 = A + (size_t)(m0 + srow) * 1024 + scc * 8;
    const unsigned short* gA1 = A + (size_t)(m0 + 64 + srow) * 1024 + scc * 8;
    const unsigned short* gB0 = B + (size_t)(n0 + srow) * 1024 + scc * 8;
    const unsigned short* gB1 = B + (size_t)(n0 + 64 + srow) * 1024 + scc * 8;

    f32x4 acc[4][4] = {};

    #pragma unroll 1
    for (int kt = 0; kt < 1024; kt += 32) {
        __syncthreads();
        GLD16(gA0, As + (size_t)t * 8);
        GLD16(gA1, As + (size_t)(t + 256) * 8);
        GLD16(gB0, Bs + (size_t)t * 8);
        GLD16(gB1, Bs + (size_t)(t + 256) * 8);
        gA0 += 32; gA1 += 32; gB0 += 32; gB1 += 32;
        __syncthreads();

        bf16x8 af[4], bf[4];
        #pragma unroll
        for (int mt = 0; mt < 4; ++mt) {
            const int r = wm + mt*16 + lrow;
            af[mt] = *(const bf16x8*)(As + r*32 + ((quad ^ ((r>>1)&3))*8));
        }
        #pragma unroll
        for (int nt = 0; nt < 4; ++nt) {
            const int r = wn + nt*16 + lrow;
            bf[nt] = *(const bf16x8*)(Bs + r*32 + ((quad ^ ((r>>1)&3))*8));
        }
        #pragma unroll
        for (int mt = 0; mt < 4; ++mt)
            #pragma unroll
            for (int nt = 0; nt < 4; ++nt)
                acc[mt][nt] = __builtin_amdgcn_mfma_f32_16x16x32_bf16(
                    af[mt], bf[nt], acc[mt][nt], 0, 0, 0);
    }

    unsigned short* dstQK = ws_out + WS_QH + (size_t)which * 4194304u;
    unsigned short* dstV  = ws_out + WS_VT;
    const float qscale = 0.18033688011112042f;   // 0.125 * log2(e)

    #pragma unroll
    for (int nt = 0; nt < 4; ++nt) {
        const int n = n0 + wn + nt*16 + lrow;
        const float bn = bias[n];
        const int h = (n & 1023) >> 6;
        const int d = n & 63;
        #pragma unroll
        for (int mt = 0; mt < 4; ++mt) {
            if (which < 2) {
                #pragma unroll
                for (int r = 0; r < 4; ++r) {
                    const int m = m0 + wm + mt*16 + quad*4 + r;
                    const int s = m >> 1, b = m & 1;
                    float val = acc[mt][nt][r] + bn;
                    if (which == 0) val *= qscale;
                    dstQK[((size_t)((b<<4) + h) * 2048 + s) * 64 + d] = f2bf(val);
                }
            } else {
                const int m_base = m0 + wm + mt*16 + quad*4;
                const int s0 = m_base >> 1;
                unsigned int pk0 = pk2bf(acc[mt][nt][0] + bn, acc[mt][nt][2] + bn);
                unsigned int pk1 = pk2bf(acc[mt][nt][1] + bn, acc[mt][nt][3] + bn);
                *(unsigned int*)(dstV + ((size_t)h*64 + d)*2048 + s0)        = pk0;
                *(unsigned int*)(dstV + ((size_t)(16 + h)*64 + d)*2048 + s0) = pk1;
            }
        }
    }
}

// ---------------------------------------------------------------------------
// Flash attention, transposed-score form, 4 waves / 64-query tile.
// Wave w owns 16 queries [w*16, w*16+16). S^T = K.Q^T (col=query domain);
// O^T = V.P^T in the same domain. l is folded into the PV MFMA via a
// constant ones-row appended to V^T (rows 64..79: row 64 = 1.0, rest 0 —
// written once, swizzle-invariant): O-tile 4, row 0 accumulates sum_k P
// with the same alpha rescaling as O, eliminating per-iter rsum/shuffles.
// ---------------------------------------------------------------------------
__global__ __launch_bounds__(256) void attn_mfma_kernel(
    const unsigned short* __restrict__ qh, const unsigned short* __restrict__ kh,
    const unsigned short* __restrict__ vt, unsigned short* __restrict__ attn)
{
    __shared__ unsigned short Qs[64*64];    // 8 KB
    __shared__ unsigned short Ks[64*64];    // 8 KB
    __shared__ unsigned short Vts[80*64];   // 10 KB (rows 64..79 constant)
    __shared__ unsigned short Ps[64*64];    // 8 KB

    const int t    = threadIdx.x;           // 0..255
    const int lane = t & 63;
    const int w    = t >> 6;                // 0..3
    const int lrow = lane & 15;
    const int quad = lane >> 4;

    const int qt = blockIdx.x;   // 0..31
    const int bh = blockIdx.y;   // 0..31

    const unsigned short* Qg = qh + ((size_t)bh * 2048 + qt * 64) * 64;
    const unsigned short* Kb = kh + (size_t)bh * 2048 * 64;
    const unsigned short* Vb = vt + (size_t)bh * 64 * 2048;

    // stage Q tile (512 chunks of 16B, 2 per thread, swizzled source)
    #pragma unroll
    for (int i = 0; i < 2; ++i) {
        const int c = i*256 + t;
        const int row = c >> 3, cc = (c & 7) ^ (row & 7);
        GLD16(Qg + (size_t)row*64 + cc*8, Qs + (size_t)c*8);
    }
    // constant V^T rows 64..79 (row 64 = ones, 65..79 = zeros)
    if (t < 128) {
        const int row = 64 + (t >> 3);
        const unsigned short fill = (row == 64) ? (unsigned short)0x3F80 : (unsigned short)0;
        u16x8 cv;
        #pragma unroll
        for (int j = 0; j < 8; ++j) cv[j] = fill;
        *(u16x8*)(Vts + row*64 + (t & 7)*8) = cv;
    }

    f32x4 O[5] = {};             // tiles 0..3 = output d; tile 4 row 0 = l
    float m_i = -INFINITY;

    #pragma unroll 1
    for (int ktile = 0; ktile < 32; ++ktile) {
        __syncthreads();
        const unsigned short* Kg = Kb + (size_t)ktile * 64 * 64;
        const unsigned short* Vg = Vb + (size_t)ktile * 64;
        #pragma unroll
        for (int i = 0; i < 2; ++i) {
            const int c = i*256 + t;
            const int row = c >> 3, cc = (c & 7) ^ (row & 7);
            GLD16(Kg + (size_t)row*64   + cc*8, Ks  + (size_t)c*8);
            GLD16(Vg + (size_t)row*2048 + cc*8, Vts + (size_t)c*8);
        }
        __syncthreads();

        // S^T = K.Q^T : ST[m], rows=keys (m*16+quad*4+r), cols=queries(lrow)
        f32x4 ST[4] = {};
        #pragma unroll
        for (int kk = 0; kk < 2; ++kk) {
            const int qr = w*16 + lrow;
            bf16x8 qf = *(const bf16x8*)(Qs + qr*64 + (((kk*4+quad) ^ (qr&7))*8));
            #pragma unroll
            for (int m = 0; m < 4; ++m) {
                const int r = m*16 + lrow;
                bf16x8 kf = *(const bf16x8*)(Ks + r*64 + (((kk*4+quad) ^ (r&7))*8));
                ST[m] = __builtin_amdgcn_mfma_f32_16x16x32_bf16(kf, qf, ST[m], 0, 0, 0);
            }
        }

        // key-max for this lane's query (15 in-reg max + 2 shfl over quads)
        float mm = fmaxf(fmaxf(ST[0][0], ST[0][1]), fmaxf(ST[0][2], ST[0][3]));
        #pragma unroll
        for (int m = 1; m < 4; ++m)
            mm = fmaxf(mm, fmaxf(fmaxf(ST[m][0], ST[m][1]),
                                 fmaxf(ST[m][2], ST[m][3])));
        mm = fmaxf(mm, __shfl_xor(mm, 16, 64));
        mm = fmaxf(mm, __shfl_xor(mm, 32, 64));

        if (__any(mm > m_i)) {
            const float mn = fmaxf(m_i, mm);
            const float al = fast_exp2(m_i - mn);
            m_i = mn;
            #pragma unroll
            for (int d = 0; d < 5; ++d) O[d] *= al;
        }

        // P = exp2(S - m), packed b64 stores to Ps[query][key]
        const int prow = w*16 + lrow;
        #pragma unroll
        for (int m = 0; m < 4; ++m) {
            const float p0 = fast_exp2(ST[m][0] - m_i);
            const float p1 = fast_exp2(ST[m][1] - m_i);
            const float p2 = fast_exp2(ST[m][2] - m_i);
            const float p3 = fast_exp2(ST[m][3] - m_i);
            uint2 pk;
            pk.x = pk2bf(p0, p1);
            pk.y = pk2bf(p2, p3);
            const int sc = (m*2 + (quad >> 1)) ^ (prow & 7);
            *(uint2*)(Ps + prow*64 + sc*8 + (quad & 1)*4) = pk;
        }

        // O^T += V.P^T  (tile 4 = ones-row -> accumulates l in row 0)
        #pragma unroll
        for (int kk = 0; kk < 2; ++kk) {
            bf16x8 pf = *(const bf16x8*)(Ps + prow*64 + (((kk*4+quad) ^ (prow&7))*8));
            #pragma unroll
            for (int d = 0; d < 5; ++d) {
                const int r = d*16 + lrow;
                bf16x8 vf = *(const bf16x8*)(Vts + r*64 + (((kk*4+quad) ^ (r&7))*8));
                O[d] = __builtin_amdgcn_mfma_f32_16x16x32_bf16(vf, pf, O[d], 0, 0, 0);
            }
        }
    }

    // epilogue: l lives in O[4][0] of quad-0 lanes (D row 64, col=query)
    const float lv = O[4][0];
    const float l  = __shfl(lv, lrow, 64);
    const float inv = 1.f / l;

    const int b_ = bh >> 4, h_ = bh & 15;
    const int s_ = qt*64 + w*16 + lrow;
    unsigned short* dst = attn + ((size_t)(s_*2 + b_)) * 1024 + h_*64;
    #pragma unroll
    for (int dt = 0; dt < 4; ++dt) {
        uint2 pk;
        pk.x = pk2bf(O[dt][0]*inv, O[dt][1]*inv);
        pk.y = pk2bf(O[dt][2]*inv, O[dt][3]*inv);
        *(uint2*)(dst + dt*16 + quad*4) = pk;
    }
}

// ---------------------------------------------------------------------------
// Out projection GEMM-BT (MFMA): 64x128 tile (512 blocks for occupancy).
// ---------------------------------------------------------------------------
__global__ __launch_bounds__(256) void out_gemm_kernel(
    const unsigned short* __restrict__ A, const unsigned short* __restrict__ B,
    const float* __restrict__ bias, float* __restrict__ out)
{
    __shared__ unsigned short As[64*32];
    __shared__ unsigned short Bs[128*32];

    const int t    = threadIdx.x;
    const int lane = t & 63;
    const int w    = t >> 6;
    const int lrow = lane & 15;
    const int quad = lane >> 4;
    const int wn   = (w >> 1) * 64;
    const int wm   = (w & 1) * 32;

    const int n0 = blockIdx.x * 128;
    const int m0 = blockIdx.y * 64;

    const int srow = t >> 2;
    const int scc  = (t & 3) ^ ((t >> 3) & 3);
    const unsigned short* gA0 = A + (size_t)(m0 + srow) * 1024 + scc * 8;
    const unsigned short* gB0 = B + (size_t)(n0 + srow) * 1024 + scc * 8;
    const unsigned short* gB1 = B + (size_t)(n0 + 64 + srow) * 1024 + scc * 8;

    f32x4 acc[2][4] = {};

    #pragma unroll 1
    for (int kt = 0; kt < 1024; kt += 32) {
        __syncthreads();
        GLD16(gA0, As + (size_t)t * 8);
        GLD16(gB0, Bs + (size_t)t * 8);
        GLD16(gB1, Bs + (size_t)(t + 256) * 8);
        gA0 += 32; gB0 += 32; gB1 += 32;
        __syncthreads();

        bf16x8 af[2], bf[4];
        #pragma unroll
        for (int mt = 0; mt < 2; ++mt) {
            const int r = wm + mt*16 + lrow;
            af[mt] = *(const bf16x8*)(As + r*32 + ((quad ^ ((r>>1)&3))*8));
        }
        #pragma unroll
        for (int nt = 0; nt < 4; ++nt) {
            const int r = wn + nt*16 + lrow;
            bf[nt] = *(const bf16x8*)(Bs + r*32 + ((quad ^ ((r>>1)&3))*8));
        }
        #pragma unroll
        for (int mt = 0; mt < 2; ++mt)
            #pragma unroll
            for (int nt = 0; nt < 4; ++nt)
                acc[mt][nt] = __builtin_amdgcn_mfma_f32_16x16x32_bf16(
                    af[mt], bf[nt], acc[mt][nt], 0, 0, 0);
    }

    #pragma unroll
    for (int nt = 0; nt < 4; ++nt) {
        const int n = n0 + wn + nt*16 + lrow;
        const float bn = bias[n];
        #pragma unroll
        for (int mt = 0; mt < 2; ++mt) {
            #pragma unroll
            for (int r = 0; r < 4; ++r) {
                const int m = m0 + wm + mt*16 + quad*4 + r;
                out[(size_t)m * 1024 + n] = acc[mt][nt][r] + bn;
            }
        }
    }
}

// ---------------------------------------------------------------------------
extern "C" void kernel_launch(void* const* d_in, const int* in_sizes, int n_in,
                              void* d_out, int out_size, void* d_ws, size_t ws_size,
                              hipStream_t stream) {
    const float* q     = (const float*)d_in[0];
    const float* k     = (const float*)d_in[1];
    const float* v     = (const float*)d_in[2];
    const float* w_in  = (const float*)d_in[3];
    const float* b_in  = (const float*)d_in[4];
    const float* w_out = (const float*)d_in[5];
    const float* b_out = (const float*)d_in[6];
    float* out = (float*)d_out;

    unsigned short* ws = (unsigned short*)d_ws;

    cast_all_kernel<<<8192, 256, 0, stream>>>(q, k, v, w_in, w_out, ws);
    qkv_gemm_kernel<<<dim3(24, 32), 256, 0, stream>>>(ws, b_in, ws);
    attn_mfma_kernel<<<dim3(32, 32), 256, 0, stream>>>(
        ws + WS_QH, ws + WS_KH, ws + WS_VT, ws + WS_ATT);
    out_gemm_kernel<<<dim3(8, 64), 256, 0, stream>>>(
        ws + WS_ATT, ws + WS_WOB, b_out, out);
}